// Round 10
// baseline (198.228 us; speedup 1.0000x reference)
//
#include <hip/hip_runtime.h>
#include <stdint.h>
#include <stddef.h>

typedef _Float16 f16;
typedef _Float16 f16x8 __attribute__((ext_vector_type(8)));
typedef _Float16 f16x4 __attribute__((ext_vector_type(4)));
typedef float f32x4 __attribute__((ext_vector_type(4)));

__device__ __forceinline__ void gload16(const void* g, void* l) {
    auto gp = (const __attribute__((address_space(1))) uint32_t*)(uintptr_t)g;
    auto lp = (__attribute__((address_space(3))) uint32_t*)(uintptr_t)l;
    __builtin_amdgcn_global_load_lds(gp, lp, 16, 0, 0);
}

__device__ __forceinline__ f16x4 cvt4(f32x4 v) {
    return f16x4{ (f16)v[0], (f16)v[1], (f16)v[2], (f16)v[3] };
}

// ---------------- prep: f32 -> f16 conversions --------------------------------
__global__ __launch_bounds__(256) void prep_k(const float* __restrict__ x,
                                              const float* __restrict__ wqkv,
                                              const float* __restrict__ wout,
                                              f16* __restrict__ xb,
                                              f16* __restrict__ wqb,
                                              f16* __restrict__ wob) {
    int tid = blockIdx.x * blockDim.x + threadIdx.x;
    int stride = gridDim.x * blockDim.x;
    for (int i = tid; i < 4194304; i += stride) {
        float4 v = ((const float4*)x)[i];
        *(f16x4*)(xb + (size_t)i * 4) = f16x4{ (f16)v.x, (f16)v.y, (f16)v.z, (f16)v.w };
    }
    for (int i = tid; i < 196608; i += stride) {
        float4 v = ((const float4*)wqkv)[i];
        *(f16x4*)(wqb + (size_t)i * 4) = f16x4{ (f16)v.x, (f16)v.y, (f16)v.z, (f16)v.w };
    }
    for (int i = tid; i < 65536; i += stride) {
        float4 v = ((const float4*)wout)[i];
        *(f16x4*)(wob + (size_t)i * 4) = f16x4{ (f16)v.x, (f16)v.y, (f16)v.z, (f16)v.w };
    }
}

#define W0  asm volatile("s_waitcnt vmcnt(0)" ::: "memory")
#define BAR __builtin_amdgcn_s_barrier()

// ======================= ENGINE C: g13 (m97-style) ============================
// 128x128 tile, BK=64, 4 waves, SINGLE-buffered 32KB LDS -> 4-5 blocks/CU.
// Per K-tile: STAGE -> vmcnt(0) -> BAR -> RD(kk0) -> MM16 -> RD(kk1) -> MM16
// -> BAR.  The in-block stage stall is covered by cross-block drift (m97/m114).
// Single 8-frag set (32 VGPR) rewritten per kk.  Used for QKV Q/K and V GEMMs.

#define C_STAGE do {                                                            \
    gload16(Ab + kb + sE,          &ldsA[( 0 + wid*8)*64]);                     \
    gload16(Ab + kb + sO + 32768,  &ldsA[(32 + wid*8)*64]);                     \
    gload16(Ab + kb + sE + 65536,  &ldsA[(64 + wid*8)*64]);                     \
    gload16(Ab + kb + sO + 98304,  &ldsA[(96 + wid*8)*64]);                     \
    gload16(Bb + kb + sE,          &ldsB[( 0 + wid*8)*64]);                     \
    gload16(Bb + kb + sO + 32768,  &ldsB[(32 + wid*8)*64]);                     \
    gload16(Bb + kb + sE + 65536,  &ldsB[(64 + wid*8)*64]);                     \
    gload16(Bb + kb + sO + 98304,  &ldsB[(96 + wid*8)*64]);                     \
    kb += 128;                                                                  \
} while (0)

#define C_RD(KK) do {                                                           \
    _Pragma("unroll") for (int ni = 0; ni < 4; ++ni)                            \
        bF[ni] = *(const f16x8*)(&ldsB[0] + boff[ni][KK]);                      \
    _Pragma("unroll") for (int mi = 0; mi < 4; ++mi)                            \
        aF[mi] = *(const f16x8*)(&ldsA[0] + aoff[mi][KK]);                      \
} while (0)

#define C_MM16 do {                                                             \
    __builtin_amdgcn_s_setprio(1);                                              \
    _Pragma("unroll") for (int mi = 0; mi < 4; ++mi)                            \
    _Pragma("unroll") for (int ni = 0; ni < 4; ++ni) {                          \
        if constexpr (SWP)                                                      \
            acc[mi][ni] = __builtin_amdgcn_mfma_f32_16x16x32_f16(               \
                bF[ni], aF[mi], acc[mi][ni], 0, 0, 0);                          \
        else                                                                    \
            acc[mi][ni] = __builtin_amdgcn_mfma_f32_16x16x32_f16(               \
                aF[mi], bF[ni], acc[mi][ni], 0, 0, 0);                          \
    }                                                                           \
    __builtin_amdgcn_s_setprio(0);                                              \
} while (0)

// MODE 0 + QK: qkv Q/K part (normal mfma, permuted A rows) -> Q/K [bh][c][lh]
// MODE 0 + SWP: qkv V part (swapped) -> V [bh][lh][d]
template <int MODE, bool SWP, bool QK>
__global__ __launch_bounds__(256) void g13_k(const f16* __restrict__ A0,
                                             const f16* __restrict__ B0,
                                             void* __restrict__ C0,
                                             void* __restrict__ C1) {
    __shared__ f16 ldsA[8192];   // 128x64, 16 KiB
    __shared__ f16 ldsB[8192];   // 128x64, 16 KiB

    const int tid = threadIdx.x;
    const int lane = tid & 63;
    const int wid = tid >> 6;
    const int wr = wid >> 1;
    const int wc = wid & 1;

    const int bid = blockIdx.x;
    int tm, tn;
    if constexpr (QK) {
        int swz = (bid & 7) * 256 + (bid >> 3);       // 2048 blocks
        tm = (swz >> 3) * 128; tn = (swz & 7) * 128;
    } else {
        int swz = (bid & 7) * 128 + (bid >> 3);       // 1024 blocks
        tm = (swz >> 2) * 128; tn = (swz & 3) * 128;
    }

    const char* Ab = (const char*)(A0 + (size_t)tm * 512);
    const char* Bb = (const char*)(B0 + (size_t)tn * 512);

    const int u = tid >> 3;
    const int colE = ((tid & 7) ^ ((u & 7) ^ (u >> 3))) * 16;
    const int sE = u * 1024 + colE;
    const int sO = sE ^ 64;
    int kb = 0;

    int aoff[4][2], boff[4][2];
#pragma unroll
    for (int mi = 0; mi < 4; ++mi) {
        int r;
        if constexpr (QK) {
            r = (lane & 15) * 8 + wr * 4 + mi;
        } else {
            r = wr * 64 + mi * 16 + (lane & 15);
        }
#pragma unroll
        for (int kk = 0; kk < 2; ++kk) {
            int c8 = (lane >> 4) + kk * 4;
            aoff[mi][kk] = r * 64 + (c8 ^ ((r & 7) ^ ((r >> 3) & 7))) * 8;
        }
    }
#pragma unroll
    for (int ni = 0; ni < 4; ++ni) {
        int r = wc * 64 + ni * 16 + (lane & 15);
#pragma unroll
        for (int kk = 0; kk < 2; ++kk) {
            int c8 = (lane >> 4) + kk * 4;
            boff[ni][kk] = r * 64 + (c8 ^ ((r & 7) ^ ((r >> 3) & 7))) * 8;
        }
    }

    f32x4 acc[4][4] = {};
    f16x8 aF[4], bF[4];

#pragma unroll 1
    for (int t = 0; t < 8; ++t) {
        C_STAGE;
        W0; BAR;
        C_RD(0);
        C_MM16;
        C_RD(1);
        C_MM16;
        BAR;
    }

    if constexpr (MODE == 0 && QK) {
        const int b = tm >> 12;
        const int lt = (tm & 4095) >> 3;
        f16* dst = (f16*)(tn < 512 ? C0 : C1);
        const int cb = (tn & 511) + wc * 64;
        const int lh0 = lt + (lane >> 4) * 4;
#pragma unroll
        for (int mi = 0; mi < 4; ++mi) {
            int h = wr * 4 + mi;
#pragma unroll
            for (int ni = 0; ni < 4; ++ni) {
                int c = cb + ni * 16 + (lane & 15);
                *(f16x4*)(dst + ((size_t)((b * 8 + h) * 512 + c)) * 512 + lh0) =
                    cvt4(acc[mi][ni]);
            }
        }
    } else {                       // V, swapped
        f16* dst = (f16*)C0;
#pragma unroll
        for (int mi = 0; mi < 4; ++mi) {
            int t = tm + wr * 64 + mi * 16 + (lane & 15);
            int b = t >> 12, l = t & 4095;
            int h = l & 7, lh = l >> 3;
#pragma unroll
            for (int ni = 0; ni < 4; ++ni) {
                int d0 = tn + wc * 64 + ni * 16 + (lane >> 4) * 4;
                *(f16x4*)(dst + ((size_t)((b * 8 + h) * 512 + lh)) * 512 + d0) =
                    cvt4(acc[mi][ni]);
            }
        }
    }
}

// ======================= ENGINE B: g12 (r8 verbatim) ==========================
// 256x256 tile, BK=64, 8 waves, per-wave 128x64, kk-phased single frag set.
// Used for the per-bh / small GEMMs: S, PV, OUT.

#define B_STAGE(NB) do {                                                        \
    gload16(At + soff,          &ldsA2[NB][(  0 + wid*8)*64]);                  \
    gload16(At + soff + 65536,  &ldsA2[NB][( 64 + wid*8)*64]);                  \
    gload16(At + soff + 131072, &ldsA2[NB][(128 + wid*8)*64]);                  \
    gload16(At + soff + 196608, &ldsA2[NB][(192 + wid*8)*64]);                  \
    gload16(Bt + soff,          &ldsB2[NB][(  0 + wid*8)*64]);                  \
    gload16(Bt + soff + 65536,  &ldsB2[NB][( 64 + wid*8)*64]);                  \
    gload16(Bt + soff + 131072, &ldsB2[NB][(128 + wid*8)*64]);                  \
    gload16(Bt + soff + 196608, &ldsB2[NB][(192 + wid*8)*64]);                  \
    At += 128; Bt += 128;                                                       \
} while (0)

#define B_RD12(KK, BUF) do {                                                    \
    _Pragma("unroll") for (int ni = 0; ni < 4; ++ni)                            \
        bF[ni] = *(const f16x8*)(&ldsB2[BUF][0] + boff[ni][KK]);                \
    _Pragma("unroll") for (int mi = 0; mi < 8; ++mi)                            \
        aF[mi] = *(const f16x8*)(&ldsA2[BUF][0] + aoff[mi][KK]);                \
} while (0)

#define B_MM32 do {                                                             \
    __builtin_amdgcn_s_setprio(1);                                              \
    _Pragma("unroll") for (int mi = 0; mi < 8; ++mi)                            \
    _Pragma("unroll") for (int ni = 0; ni < 4; ++ni) {                          \
        if constexpr (SWP)                                                      \
            acc[mi][ni] = __builtin_amdgcn_mfma_f32_16x16x32_f16(               \
                bF[ni], aF[mi], acc[mi][ni], 0, 0, 0);                          \
        else                                                                    \
            acc[mi][ni] = __builtin_amdgcn_mfma_f32_16x16x32_f16(               \
                aF[mi], bF[ni], acc[mi][ni], 0, 0, 0);                          \
    }                                                                           \
    __builtin_amdgcn_s_setprio(0);                                              \
} while (0)

#define B_TILE(CB, NB, STG, FINAL) do {                                         \
    B_RD12(0, CB);                                                              \
    if (STG) B_STAGE(NB);                                                       \
    B_MM32;                                                                     \
    B_RD12(1, CB);                                                              \
    B_MM32;                                                                     \
    if (!FINAL) { W0; BAR; }                                                    \
} while (0)

// MODE 1: S = Q K^T * 0.125 per bh (swapped, f16 out)
// MODE 2: Y = P V per bh (normal, f16 out to y[token][c])
// MODE 3: out = y w_out^T + b_out (swapped, f32 out)
template <int MODE, bool SWP>
__global__ __launch_bounds__(512) void g12_k(const f16* __restrict__ A0,
                                             const f16* __restrict__ B0,
                                             void* __restrict__ C0,
                                             const float* __restrict__ bias) {
    __shared__ f16 ldsA2[2][16384];
    __shared__ f16 ldsB2[2][16384];

    const int tid = threadIdx.x;
    const int lane = tid & 63;
    const int wid = tid >> 6;
    const int wr = wid >> 2;
    const int wc = wid & 3;

    const int bid = blockIdx.x;
    int tm, tn, bh = 0;
    if constexpr (MODE == 1 || MODE == 2) {
        int swz = (bid & 7) * 32 + (bid >> 3);        // 256 blocks
        bh = swz >> 2; tm = ((swz >> 1) & 1) * 256; tn = (swz & 1) * 256;
    } else {
        int swz = (bid & 7) * 32 + (bid >> 3);        // 256 blocks
        tm = (swz >> 1) * 256; tn = (swz & 1) * 256;
    }

    const size_t bhoff = (MODE == 1 || MODE == 2) ? (size_t)bh * 262144 : 0;
    const char* At = (const char*)(A0 + bhoff + (size_t)tm * 512);
    const char* Bt = (const char*)(B0 + bhoff + (size_t)tn * 512);

    const int soff = wid * 8192 + (lane >> 3) * 1024 +
                     ((((lane & 7) ^ (lane >> 3) ^ wid) & 7) * 16);

    int aoff[8][2], boff[4][2];
#pragma unroll
    for (int mi = 0; mi < 8; ++mi) {
        int r = wr * 128 + mi * 16 + (lane & 15);
        int s3 = (r & 7) ^ ((r >> 3) & 7);
#pragma unroll
        for (int kk = 0; kk < 2; ++kk)
            aoff[mi][kk] = r * 64 + ((((lane >> 4) + kk * 4) ^ s3)) * 8;
    }
#pragma unroll
    for (int ni = 0; ni < 4; ++ni) {
        int r = wc * 64 + ni * 16 + (lane & 15);
        int s3 = (r & 7) ^ ((r >> 3) & 7);
#pragma unroll
        for (int kk = 0; kk < 2; ++kk)
            boff[ni][kk] = r * 64 + ((((lane >> 4) + kk * 4) ^ s3)) * 8;
    }

    f32x4 acc[8][4] = {};
    f16x8 aF[8], bF[4];

    B_STAGE(0);
    W0; BAR;

#pragma unroll 1
    for (int i = 0; i < 3; ++i) {
        B_TILE(0, 1, true, false);
        B_TILE(1, 0, true, false);
    }
    B_TILE(0, 1, true, false);    // t6
    B_TILE(1, 1, false, true);    // t7

    if constexpr (MODE == 1) {
        f16* S = (f16*)C0 + (size_t)bh * 262144;
#pragma unroll
        for (int mi = 0; mi < 8; ++mi) {
            int cm = tm + wr * 128 + mi * 16 + (lane & 15);
#pragma unroll
            for (int ni = 0; ni < 4; ++ni) {
                int d0 = tn + wc * 64 + ni * 16 + (lane >> 4) * 4;
                *(f16x4*)(S + (size_t)cm * 512 + d0) = cvt4(acc[mi][ni] * 0.125f);
            }
        }
    } else if constexpr (MODE == 2) {
        f16* yb = (f16*)C0;
        const int b = bh >> 3, h = bh & 7;
#pragma unroll
        for (int mi = 0; mi < 8; ++mi) {
            int c0 = tm + wr * 128 + mi * 16 + (lane >> 4) * 4;
#pragma unroll
            for (int ni = 0; ni < 4; ++ni) {
                int l = tn + wc * 64 + ni * 16 + (lane & 15);
                size_t tok = (size_t)b * 4096 + (size_t)l * 8 + h;
                *(f16x4*)(yb + tok * 512 + c0) = cvt4(acc[mi][ni]);
            }
        }
    } else {
        float* O = (float*)C0;
#pragma unroll
        for (int mi = 0; mi < 8; ++mi) {
            int m = tm + wr * 128 + mi * 16 + (lane & 15);
#pragma unroll
            for (int ni = 0; ni < 4; ++ni) {
                int n0 = tn + wc * 64 + ni * 16 + (lane >> 4) * 4;
                float4 bv = *(const float4*)(bias + n0);
                f32x4 v = acc[mi][ni];
                v[0] += bv.x; v[1] += bv.y; v[2] += bv.z; v[3] += bv.w;
                *(f32x4*)(O + (size_t)m * 512 + n0) = v;
            }
        }
    }
}

// ---------------- softmax over 512-wide rows (wave per row, f16 in/out) -------
__global__ __launch_bounds__(256) void softmax_k(const f16* __restrict__ S,
                                                 f16* __restrict__ P) {
    int row = blockIdx.x * 4 + (threadIdx.x >> 6);
    int lane = threadIdx.x & 63;
    f16x8 v = *(const f16x8*)(S + (size_t)row * 512 + lane * 8);
    float f[8];
#pragma unroll
    for (int i = 0; i < 8; ++i) f[i] = (float)v[i];
    float m = f[0];
#pragma unroll
    for (int i = 1; i < 8; ++i) m = fmaxf(m, f[i]);
#pragma unroll
    for (int off = 1; off < 64; off <<= 1) m = fmaxf(m, __shfl_xor(m, off, 64));
    float s = 0.f, e[8];
#pragma unroll
    for (int i = 0; i < 8; ++i) { e[i] = __expf(f[i] - m); s += e[i]; }
#pragma unroll
    for (int off = 1; off < 64; off <<= 1) s += __shfl_xor(s, off, 64);
    float inv = 1.0f / s;
    f16x8 pk;
#pragma unroll
    for (int i = 0; i < 8; ++i) pk[i] = (f16)(e[i] * inv);
    *(f16x8*)(P + (size_t)row * 512 + lane * 8) = pk;
}

// ---------------- launch ------------------------------------------------------
extern "C" void kernel_launch(void* const* d_in, const int* in_sizes, int n_in,
                              void* d_out, int out_size, void* d_ws, size_t ws_size,
                              hipStream_t stream) {
    const float* x = (const float*)d_in[0];
    const float* wqkv = (const float*)d_in[1];
    const float* wout = (const float*)d_in[2];
    const float* bout = (const float*)d_in[3];
    float* out = (float*)d_out;
    char* ws = (char*)d_ws;
    const size_t MBs = 1u << 20;

    f16* xb  = (f16*)(ws + 0);            // 32MB
    f16* wqb = (f16*)(ws + 32 * MBs);     // 1.5MB
    f16* wob = (f16*)(ws + 34 * MBs);     // 0.5MB
    f16* Qb  = (f16*)(ws + 35 * MBs);     // 32MB
    f16* Kb  = (f16*)(ws + 67 * MBs);     // 32MB
    f16* Vb  = (f16*)(ws + 99 * MBs);     // 32MB
    f16* Sb  = (f16*)(ws + 131 * MBs);    // 32MB (total 163MB)
    f16* Pb  = xb;                        // alias: xb dead after V GEMM
    f16* yb  = Qb;                        // alias: Q dead after S GEMM

    prep_k<<<1024, 256, 0, stream>>>(x, wqkv, wout, xb, wqb, wob);
    g13_k<0, false, true><<<2048, 256, 0, stream>>>(xb, wqb, Qb, Kb);
    g13_k<0, true, false><<<1024, 256, 0, stream>>>(xb, wqb + (size_t)1024 * 512, Vb, nullptr);
    g12_k<1, true><<<256, 512, 0, stream>>>(Qb, Kb, Sb, nullptr);
    softmax_k<<<8192, 256, 0, stream>>>(Sb, Pb);
    g12_k<2, false><<<256, 512, 0, stream>>>(Pb, Vb, yb, nullptr);
    g12_k<3, true><<<256, 512, 0, stream>>>(yb, wob, out, bout);
}

// Round 11
// 193.227 us; speedup vs baseline: 1.0259x; 1.0259x over previous
//
#include <hip/hip_runtime.h>
#include <stdint.h>
#include <stddef.h>

typedef _Float16 f16;
typedef _Float16 f16x8 __attribute__((ext_vector_type(8)));
typedef _Float16 f16x4 __attribute__((ext_vector_type(4)));
typedef float f32x4 __attribute__((ext_vector_type(4)));

__device__ __forceinline__ void gload16(const void* g, void* l) {
    auto gp = (const __attribute__((address_space(1))) uint32_t*)(uintptr_t)g;
    auto lp = (__attribute__((address_space(3))) uint32_t*)(uintptr_t)l;
    __builtin_amdgcn_global_load_lds(gp, lp, 16, 0, 0);
}

__device__ __forceinline__ f16x4 cvt4(f32x4 v) {
    return f16x4{ (f16)v[0], (f16)v[1], (f16)v[2], (f16)v[3] };
}

// ---------------- prep: f32 -> f16 conversions --------------------------------
__global__ __launch_bounds__(256) void prep_k(const float* __restrict__ x,
                                              const float* __restrict__ wqkv,
                                              const float* __restrict__ wout,
                                              f16* __restrict__ xb,
                                              f16* __restrict__ wqb,
                                              f16* __restrict__ wob) {
    int tid = blockIdx.x * blockDim.x + threadIdx.x;
    int stride = gridDim.x * blockDim.x;
    for (int i = tid; i < 4194304; i += stride) {
        float4 v = ((const float4*)x)[i];
        *(f16x4*)(xb + (size_t)i * 4) = f16x4{ (f16)v.x, (f16)v.y, (f16)v.z, (f16)v.w };
    }
    for (int i = tid; i < 196608; i += stride) {
        float4 v = ((const float4*)wqkv)[i];
        *(f16x4*)(wqb + (size_t)i * 4) = f16x4{ (f16)v.x, (f16)v.y, (f16)v.z, (f16)v.w };
    }
    for (int i = tid; i < 65536; i += stride) {
        float4 v = ((const float4*)wout)[i];
        *(f16x4*)(wob + (size_t)i * 4) = f16x4{ (f16)v.x, (f16)v.y, (f16)v.z, (f16)v.w };
    }
}

#define W0  asm volatile("s_waitcnt vmcnt(0)" ::: "memory")
#define BAR __builtin_amdgcn_s_barrier()

// ======================= ENGINE A: g10 (r6/r9 verbatim) =======================
// 128x128 tile, BK=64, 4 waves, dbuf 64KB LDS, 2 blocks/CU. Zero-spill verified.
// Used for the big-M GEMMs: QKV Q/K part and V part.

#define A_STAGE(NB) do {                                                        \
    gload16(Ab + kb + sE,          &ldsA[NB][( 0 + wid*8)*64]);                 \
    gload16(Ab + kb + sO + 32768,  &ldsA[NB][(32 + wid*8)*64]);                 \
    gload16(Ab + kb + sE + 65536,  &ldsA[NB][(64 + wid*8)*64]);                 \
    gload16(Ab + kb + sO + 98304,  &ldsA[NB][(96 + wid*8)*64]);                 \
    gload16(Bb + kb + sE,          &ldsB[NB][( 0 + wid*8)*64]);                 \
    gload16(Bb + kb + sO + 32768,  &ldsB[NB][(32 + wid*8)*64]);                 \
    gload16(Bb + kb + sE + 65536,  &ldsB[NB][(64 + wid*8)*64]);                 \
    gload16(Bb + kb + sO + 98304,  &ldsB[NB][(96 + wid*8)*64]);                 \
    kb += 128;                                                                  \
} while (0)

#define A_RD(SET, BUF) do {                                                     \
    _Pragma("unroll") for (int mi = 0; mi < 4; ++mi)                            \
    _Pragma("unroll") for (int kk = 0; kk < 2; ++kk)                            \
        aF##SET[mi][kk] = *(const f16x8*)(&ldsA[BUF][0] + aoff[mi][kk]);        \
    _Pragma("unroll") for (int ni = 0; ni < 4; ++ni)                            \
    _Pragma("unroll") for (int kk = 0; kk < 2; ++kk)                            \
        bF##SET[ni][kk] = *(const f16x8*)(&ldsB[BUF][0] + boff[ni][kk]);        \
} while (0)

#define A_MM(SET, KK, ML, MH_) do {                                             \
    __builtin_amdgcn_s_setprio(1);                                              \
    _Pragma("unroll") for (int mi = ML; mi < MH_; ++mi)                         \
    _Pragma("unroll") for (int ni = 0; ni < 4; ++ni) {                          \
        if constexpr (SWP)                                                      \
            acc[mi][ni] = __builtin_amdgcn_mfma_f32_16x16x32_f16(               \
                bF##SET[ni][KK], aF##SET[mi][KK], acc[mi][ni], 0, 0, 0);        \
        else                                                                    \
            acc[mi][ni] = __builtin_amdgcn_mfma_f32_16x16x32_f16(               \
                aF##SET[mi][KK], bF##SET[ni][KK], acc[mi][ni], 0, 0, 0);        \
    }                                                                           \
    __builtin_amdgcn_s_setprio(0);                                              \
} while (0)

#define A_MM3(SET)   do { A_MM(SET, 0, 0, 2); A_MM(SET, 0, 2, 4); A_MM(SET, 1, 0, 2); } while (0)
#define A_MMLAST(SET) A_MM(SET, 1, 2, 4)

#define A_TILE(CUR, NXT, NB, STG, FINAL) do {                                   \
    if (STG) A_STAGE(NB);                                                       \
    A_MM3(CUR);                                                                 \
    if (!FINAL) { W0; BAR; A_RD(NXT, NB); }                                     \
    A_MMLAST(CUR);                                                              \
} while (0)

template <int MODE, bool SWP, bool QK>
__global__ __launch_bounds__(256, 2) void g10_k(const f16* __restrict__ A0,
                                                const f16* __restrict__ B0,
                                                void* __restrict__ C0,
                                                void* __restrict__ C1,
                                                const float* __restrict__ bias) {
    __shared__ f16 ldsA[2][8192];
    __shared__ f16 ldsB[2][8192];

    const int tid = threadIdx.x;
    const int lane = tid & 63;
    const int wid = tid >> 6;
    const int wr = wid >> 1;
    const int wc = wid & 1;

    const int bid = blockIdx.x;
    int tm, tn;
    if constexpr (MODE == 0 && QK) {
        int swz = (bid & 7) * 256 + (bid >> 3);       // 2048 blocks
        tm = (swz >> 3) * 128; tn = (swz & 7) * 128;
    } else {
        int swz = (bid & 7) * 128 + (bid >> 3);       // 1024 blocks
        tm = (swz >> 2) * 128; tn = (swz & 3) * 128;
    }

    const char* Ab = (const char*)(A0 + (size_t)tm * 512);
    const char* Bb = (const char*)(B0 + (size_t)tn * 512);

    const int u = tid >> 3;
    const int colE = ((tid & 7) ^ ((u & 7) ^ (u >> 3))) * 16;
    const int sE = u * 1024 + colE;
    const int sO = sE ^ 64;
    int kb = 0;

    int aoff[4][2], boff[4][2];
#pragma unroll
    for (int mi = 0; mi < 4; ++mi) {
        int r;
        if constexpr (QK) {
            r = (lane & 15) * 8 + wr * 4 + mi;
        } else {
            r = wr * 64 + mi * 16 + (lane & 15);
        }
#pragma unroll
        for (int kk = 0; kk < 2; ++kk) {
            int c8 = (lane >> 4) + kk * 4;
            aoff[mi][kk] = r * 64 + (c8 ^ ((r & 7) ^ ((r >> 3) & 7))) * 8;
        }
    }
#pragma unroll
    for (int ni = 0; ni < 4; ++ni) {
        int r = wc * 64 + ni * 16 + (lane & 15);
#pragma unroll
        for (int kk = 0; kk < 2; ++kk) {
            int c8 = (lane >> 4) + kk * 4;
            boff[ni][kk] = r * 64 + (c8 ^ ((r & 7) ^ ((r >> 3) & 7))) * 8;
        }
    }

    f32x4 acc[4][4] = {};
    f16x8 aF0[4][2], bF0[4][2], aF1[4][2], bF1[4][2];

    A_STAGE(0);
    W0; BAR;
    A_RD(0, 0);

#pragma unroll 1
    for (int i = 0; i < 3; ++i) {
        A_TILE(0, 1, 1, true, false);
        A_TILE(1, 0, 0, true, false);
    }
    A_TILE(0, 1, 1, true, false);   // t6
    A_TILE(1, 1, 1, false, true);   // t7

    if constexpr (MODE == 0 && QK) {
        const int b = tm >> 12;
        const int lt = (tm & 4095) >> 3;
        f16* dst = (f16*)(tn < 512 ? C0 : C1);
        const int cb = (tn & 511) + wc * 64;
        const int lh0 = lt + (lane >> 4) * 4;
#pragma unroll
        for (int mi = 0; mi < 4; ++mi) {
            int h = wr * 4 + mi;
#pragma unroll
            for (int ni = 0; ni < 4; ++ni) {
                int c = cb + ni * 16 + (lane & 15);
                *(f16x4*)(dst + ((size_t)((b * 8 + h) * 512 + c)) * 512 + lh0) =
                    cvt4(acc[mi][ni]);
            }
        }
    } else {                       // V, swapped
        f16* dst = (f16*)C0;
#pragma unroll
        for (int mi = 0; mi < 4; ++mi) {
            int t = tm + wr * 64 + mi * 16 + (lane & 15);
            int b = t >> 12, l = t & 4095;
            int h = l & 7, lh = l >> 3;
#pragma unroll
            for (int ni = 0; ni < 4; ++ni) {
                int d0 = tn + wc * 64 + ni * 16 + (lane >> 4) * 4;
                *(f16x4*)(dst + ((size_t)((b * 8 + h) * 512 + lh)) * 512 + d0) =
                    cvt4(acc[mi][ni]);
            }
        }
    }
}

// ================== ENGINE S: fused S = QK^T*scale + row softmax ==============
// Per block: one bh, one 128-row c-tile, FULL d=512 width. 8 waves, wave w owns
// d-strip w*64. acc[8][4] (mi over 128 c, ni over 64 d) = 128 AGPR. Q-tile
// 16KB + K 64KB single-buffered + 4.5KB reduce = 85KB LDS, 1 block/CU.
// Epilogue: row max (lane-local 4, shfl_xor over lane&15, 8-wave LDS combine),
// exp + row sum likewise, P = exp(S*0.125 - m)/sum written f16 to Pb [c][d].

#define S_STAGE do {                                                            \
    gload16(Qt + kb + soff,           &ldsA[(  0 + wid*8)*64]);                 \
    gload16(Qt + kb + soff + 65536,   &ldsA[( 64 + wid*8)*64]);                 \
    gload16(Kt + kb + soff,           &ldsB[(  0 + wid*8)*64]);                 \
    gload16(Kt + kb + soff + 65536,   &ldsB[( 64 + wid*8)*64]);                 \
    gload16(Kt + kb + soff + 131072,  &ldsB[(128 + wid*8)*64]);                 \
    gload16(Kt + kb + soff + 196608,  &ldsB[(192 + wid*8)*64]);                 \
    gload16(Kt + kb + soff + 262144,  &ldsB[(256 + wid*8)*64]);                 \
    gload16(Kt + kb + soff + 327680,  &ldsB[(320 + wid*8)*64]);                 \
    gload16(Kt + kb + soff + 393216,  &ldsB[(384 + wid*8)*64]);                 \
    gload16(Kt + kb + soff + 458752,  &ldsB[(448 + wid*8)*64]);                 \
    kb += 128;                                                                  \
} while (0)

#define S_RD(KK) do {                                                           \
    _Pragma("unroll") for (int ni = 0; ni < 4; ++ni)                            \
        bF[ni] = *(const f16x8*)(&ldsB[0] + boff[ni][KK]);                      \
    _Pragma("unroll") for (int mi = 0; mi < 8; ++mi)                            \
        aF[mi] = *(const f16x8*)(&ldsA[0] + aoff[mi][KK]);                      \
} while (0)

#define S_MM do {                                                               \
    __builtin_amdgcn_s_setprio(1);                                              \
    _Pragma("unroll") for (int mi = 0; mi < 8; ++mi)                            \
    _Pragma("unroll") for (int ni = 0; ni < 4; ++ni)                            \
        acc[mi][ni] = __builtin_amdgcn_mfma_f32_16x16x32_f16(                   \
            aF[mi], bF[ni], acc[mi][ni], 0, 0, 0);                              \
    __builtin_amdgcn_s_setprio(0);                                              \
} while (0)

__global__ __launch_bounds__(512) void sfm_k(const f16* __restrict__ Qb,
                                             const f16* __restrict__ Kb,
                                             f16* __restrict__ Pb) {
    __shared__ f16 ldsA[128 * 64];    // 16 KB
    __shared__ f16 ldsB[512 * 64];    // 64 KB
    __shared__ float red[8 * 128];    // 4 KB  wave partials
    __shared__ float redg[128];       // 0.5KB combined

    const int tid = threadIdx.x;
    const int lane = tid & 63;
    const int wid = tid >> 6;
    const int g = lane >> 4;          // 0..3
    const int li = lane & 15;

    const int bid = blockIdx.x;
    const int swz = (bid & 7) * 32 + (bid >> 3);   // 256 blocks, bijective
    const int bh = swz >> 2, ct = swz & 3;

    const char* Qt = (const char*)(Qb + (size_t)bh * 262144 + (size_t)ct * 128 * 512);
    const char* Kt = (const char*)(Kb + (size_t)bh * 262144);

    // staging: row64 = tid>>3 within each 64-row pass; s3(row) = (lane>>3)^wid
    const int soff = (tid >> 3) * 1024 +
                     ((((lane & 7) ^ (lane >> 3) ^ wid) & 7) * 16);
    int kb = 0;

    int aoff[8][2], boff[4][2];
#pragma unroll
    for (int mi = 0; mi < 8; ++mi) {
        int r = mi * 16 + li;
        int s3 = (r & 7) ^ ((r >> 3) & 7);
#pragma unroll
        for (int kk = 0; kk < 2; ++kk)
            aoff[mi][kk] = r * 64 + (((g + kk * 4) ^ s3)) * 8;
    }
#pragma unroll
    for (int ni = 0; ni < 4; ++ni) {
        int r = wid * 64 + ni * 16 + li;
        int s3 = (r & 7) ^ ((r >> 3) & 7);
#pragma unroll
        for (int kk = 0; kk < 2; ++kk)
            boff[ni][kk] = r * 64 + (((g + kk * 4) ^ s3)) * 8;
    }

    f32x4 acc[8][4] = {};
    f16x8 aF[8], bF[4];

#pragma unroll 1
    for (int t = 0; t < 8; ++t) {
        S_STAGE;
        W0; BAR;
        S_RD(0);
        S_MM;
        S_RD(1);
        S_MM;
        BAR;
    }

    // ---- softmax epilogue (fp32) ----
    // scale
#pragma unroll
    for (int mi = 0; mi < 8; ++mi)
#pragma unroll
        for (int ni = 0; ni < 4; ++ni) acc[mi][ni] *= 0.125f;

    // phase A: wave-partial row max over this wave's 64 cols
#pragma unroll
    for (int mi = 0; mi < 8; ++mi)
#pragma unroll
        for (int j = 0; j < 4; ++j) {
            float v = fmaxf(fmaxf(acc[mi][0][j], acc[mi][1][j]),
                            fmaxf(acc[mi][2][j], acc[mi][3][j]));
#pragma unroll
            for (int off = 1; off < 16; off <<= 1) v = fmaxf(v, __shfl_xor(v, off, 64));
            if (li == 0) red[wid * 128 + mi * 16 + g * 4 + j] = v;
        }
    BAR;
    if (tid < 128) {
        float m = red[tid];
#pragma unroll
        for (int w = 1; w < 8; ++w) m = fmaxf(m, red[w * 128 + tid]);
        redg[tid] = m;
    }
    BAR;

    // phase B: exp + wave-partial row sum
#pragma unroll
    for (int mi = 0; mi < 8; ++mi)
#pragma unroll
        for (int j = 0; j < 4; ++j) {
            float mg = redg[mi * 16 + g * 4 + j];
            float s = 0.f;
#pragma unroll
            for (int ni = 0; ni < 4; ++ni) {
                float e = __expf(acc[mi][ni][j] - mg);
                acc[mi][ni][j] = e;
                s += e;
            }
#pragma unroll
            for (int off = 1; off < 16; off <<= 1) s += __shfl_xor(s, off, 64);
            if (li == 0) red[wid * 128 + mi * 16 + g * 4 + j] = s;
        }
    BAR;
    if (tid < 128) {
        float s = red[tid];
#pragma unroll
        for (int w = 1; w < 8; ++w) s += red[w * 128 + tid];
        redg[tid] = 1.0f / s;
    }
    BAR;

    // phase C: normalize + store P[c][d]
    f16* Pt = Pb + (size_t)bh * 262144;
#pragma unroll
    for (int mi = 0; mi < 8; ++mi)
#pragma unroll
        for (int j = 0; j < 4; ++j) {
            int row = mi * 16 + g * 4 + j;
            float is = redg[row];
            size_t base = (size_t)(ct * 128 + row) * 512 + wid * 64 + li;
#pragma unroll
            for (int ni = 0; ni < 4; ++ni)
                Pt[base + ni * 16] = (f16)(acc[mi][ni][j] * is);
        }
}

// ======================= ENGINE B: g12 (r9 verbatim) ==========================
// 256x256 tile, BK=64, 8 waves, per-wave 128x64, kk-phased single frag set.
// Used for PV and OUT.

#define B_STAGE(NB) do {                                                        \
    gload16(At + soff,          &ldsA2[NB][(  0 + wid*8)*64]);                  \
    gload16(At + soff + 65536,  &ldsA2[NB][( 64 + wid*8)*64]);                  \
    gload16(At + soff + 131072, &ldsA2[NB][(128 + wid*8)*64]);                  \
    gload16(At + soff + 196608, &ldsA2[NB][(192 + wid*8)*64]);                  \
    gload16(Bt + soff,          &ldsB2[NB][(  0 + wid*8)*64]);                  \
    gload16(Bt + soff + 65536,  &ldsB2[NB][( 64 + wid*8)*64]);                  \
    gload16(Bt + soff + 131072, &ldsB2[NB][(128 + wid*8)*64]);                  \
    gload16(Bt + soff + 196608, &ldsB2[NB][(192 + wid*8)*64]);                  \
    At += 128; Bt += 128;                                                       \
} while (0)

#define B_RD12(KK, BUF) do {                                                    \
    _Pragma("unroll") for (int ni = 0; ni < 4; ++ni)                            \
        bF[ni] = *(const f16x8*)(&ldsB2[BUF][0] + boff[ni][KK]);                \
    _Pragma("unroll") for (int mi = 0; mi < 8; ++mi)                            \
        aF[mi] = *(const f16x8*)(&ldsA2[BUF][0] + aoff[mi][KK]);                \
} while (0)

#define B_MM32 do {                                                             \
    __builtin_amdgcn_s_setprio(1);                                              \
    _Pragma("unroll") for (int mi = 0; mi < 8; ++mi)                            \
    _Pragma("unroll") for (int ni = 0; ni < 4; ++ni) {                          \
        if constexpr (SWP)                                                      \
            acc[mi][ni] = __builtin_amdgcn_mfma_f32_16x16x32_f16(               \
                bF[ni], aF[mi], acc[mi][ni], 0, 0, 0);                          \
        else                                                                    \
            acc[mi][ni] = __builtin_amdgcn_mfma_f32_16x16x32_f16(               \
                aF[mi], bF[ni], acc[mi][ni], 0, 0, 0);                          \
    }                                                                           \
    __builtin_amdgcn_s_setprio(0);                                              \
} while (0)

#define B_TILE(CB, NB, STG, FINAL) do {                                         \
    B_RD12(0, CB);                                                              \
    if (STG) B_STAGE(NB);                                                       \
    B_MM32;                                                                     \
    B_RD12(1, CB);                                                              \
    B_MM32;                                                                     \
    if (!FINAL) { W0; BAR; }                                                    \
} while (0)

// MODE 2: Y = P V per bh (normal, f16 out to y[token][c])
// MODE 3: out = y w_out^T + b_out (swapped, f32 out)
template <int MODE, bool SWP>
__global__ __launch_bounds__(512) void g12_k(const f16* __restrict__ A0,
                                             const f16* __restrict__ B0,
                                             void* __restrict__ C0,
                                             const float* __restrict__ bias) {
    __shared__ f16 ldsA2[2][16384];
    __shared__ f16 ldsB2[2][16384];

    const int tid = threadIdx.x;
    const int lane = tid & 63;
    const int wid = tid >> 6;
    const int wr = wid >> 2;
    const int wc = wid & 3;

    const int bid = blockIdx.x;
    int tm, tn, bh = 0;
    if constexpr (MODE == 2) {
        int swz = (bid & 7) * 32 + (bid >> 3);        // 256 blocks
        bh = swz >> 2; tm = ((swz >> 1) & 1) * 256; tn = (swz & 1) * 256;
    } else {
        int swz = (bid & 7) * 32 + (bid >> 3);        // 256 blocks
        tm = (swz >> 1) * 256; tn = (swz & 1) * 256;
    }

    const size_t bhoff = (MODE == 2) ? (size_t)bh * 262144 : 0;
    const char* At = (const char*)(A0 + bhoff + (size_t)tm * 512);
    const char* Bt = (const char*)(B0 + bhoff + (size_t)tn * 512);

    const int soff = wid * 8192 + (lane >> 3) * 1024 +
                     ((((lane & 7) ^ (lane >> 3) ^ wid) & 7) * 16);

    int aoff[8][2], boff[4][2];
#pragma unroll
    for (int mi = 0; mi < 8; ++mi) {
        int r = wr * 128 + mi * 16 + (lane & 15);
        int s3 = (r & 7) ^ ((r >> 3) & 7);
#pragma unroll
        for (int kk = 0; kk < 2; ++kk)
            aoff[mi][kk] = r * 64 + ((((lane >> 4) + kk * 4) ^ s3)) * 8;
    }
#pragma unroll
    for (int ni = 0; ni < 4; ++ni) {
        int r = wc * 64 + ni * 16 + (lane & 15);
        int s3 = (r & 7) ^ ((r >> 3) & 7);
#pragma unroll
        for (int kk = 0; kk < 2; ++kk)
            boff[ni][kk] = r * 64 + ((((lane >> 4) + kk * 4) ^ s3)) * 8;
    }

    f32x4 acc[8][4] = {};
    f16x8 aF[8], bF[4];

    B_STAGE(0);
    W0; BAR;

#pragma unroll 1
    for (int i = 0; i < 3; ++i) {
        B_TILE(0, 1, true, false);
        B_TILE(1, 0, true, false);
    }
    B_TILE(0, 1, true, false);    // t6
    B_TILE(1, 1, false, true);    // t7

    if constexpr (MODE == 2) {
        f16* yb = (f16*)C0;
        const int b = bh >> 3, h = bh & 7;
#pragma unroll
        for (int mi = 0; mi < 8; ++mi) {
            int c0 = tm + wr * 128 + mi * 16 + (lane >> 4) * 4;
#pragma unroll
            for (int ni = 0; ni < 4; ++ni) {
                int l = tn + wc * 64 + ni * 16 + (lane & 15);
                size_t tok = (size_t)b * 4096 + (size_t)l * 8 + h;
                *(f16x4*)(yb + tok * 512 + c0) = cvt4(acc[mi][ni]);
            }
        }
    } else {
        float* O = (float*)C0;
#pragma unroll
        for (int mi = 0; mi < 8; ++mi) {
            int m = tm + wr * 128 + mi * 16 + (lane & 15);
#pragma unroll
            for (int ni = 0; ni < 4; ++ni) {
                int n0 = tn + wc * 64 + ni * 16 + (lane >> 4) * 4;
                float4 bv = *(const float4*)(bias + n0);
                f32x4 v = acc[mi][ni];
                v[0] += bv.x; v[1] += bv.y; v[2] += bv.z; v[3] += bv.w;
                *(f32x4*)(O + (size_t)m * 512 + n0) = v;
            }
        }
    }
}

// ---------------- launch ------------------------------------------------------
extern "C" void kernel_launch(void* const* d_in, const int* in_sizes, int n_in,
                              void* d_out, int out_size, void* d_ws, size_t ws_size,
                              hipStream_t stream) {
    const float* x = (const float*)d_in[0];
    const float* wqkv = (const float*)d_in[1];
    const float* wout = (const float*)d_in[2];
    const float* bout = (const float*)d_in[3];
    float* out = (float*)d_out;
    char* ws = (char*)d_ws;
    const size_t MBs = 1u << 20;

    f16* xb  = (f16*)(ws + 0);            // 32MB
    f16* wqb = (f16*)(ws + 32 * MBs);     // 1.5MB
    f16* wob = (f16*)(ws + 34 * MBs);     // 0.5MB
    f16* Qb  = (f16*)(ws + 35 * MBs);     // 32MB
    f16* Kb  = (f16*)(ws + 67 * MBs);     // 32MB
    f16* Vb  = (f16*)(ws + 99 * MBs);     // 32MB
    f16* Pb  = xb;                        // alias: xb dead after V GEMM
    f16* yb  = Qb;                        // alias: Q dead after sfm

    prep_k<<<1024, 256, 0, stream>>>(x, wqkv, wout, xb, wqb, wob);
    g10_k<0, false, true><<<2048, 256, 0, stream>>>(xb, wqb, Qb, Kb, nullptr);
    g10_k<0, true, false><<<1024, 256, 0, stream>>>(xb, wqb + (size_t)1024 * 512, Vb, nullptr, nullptr);
    sfm_k<<<256, 512, 0, stream>>>(Qb, Kb, Pb);
    g12_k<2, false><<<256, 512, 0, stream>>>(Pb, Vb, yb, nullptr);
    g12_k<3, true><<<256, 512, 0, stream>>>(yb, wob, out, bout);
}

// Round 12
// 190.509 us; speedup vs baseline: 1.0405x; 1.0143x over previous
//
#include <hip/hip_runtime.h>
#include <stdint.h>
#include <stddef.h>

typedef _Float16 f16;
typedef _Float16 f16x8 __attribute__((ext_vector_type(8)));
typedef _Float16 f16x4 __attribute__((ext_vector_type(4)));
typedef float f32x4 __attribute__((ext_vector_type(4)));

__device__ __forceinline__ void gload16(const void* g, void* l) {
    auto gp = (const __attribute__((address_space(1))) uint32_t*)(uintptr_t)g;
    auto lp = (__attribute__((address_space(3))) uint32_t*)(uintptr_t)l;
    __builtin_amdgcn_global_load_lds(gp, lp, 16, 0, 0);
}

__device__ __forceinline__ f16x4 cvt4(f32x4 v) {
    return f16x4{ (f16)v[0], (f16)v[1], (f16)v[2], (f16)v[3] };
}

// ---------------- prep: f32 -> f16 conversions --------------------------------
__global__ __launch_bounds__(256) void prep_k(const float* __restrict__ x,
                                              const float* __restrict__ wqkv,
                                              const float* __restrict__ wout,
                                              f16* __restrict__ xb,
                                              f16* __restrict__ wqb,
                                              f16* __restrict__ wob) {
    int tid = blockIdx.x * blockDim.x + threadIdx.x;
    int stride = gridDim.x * blockDim.x;
    for (int i = tid; i < 4194304; i += stride) {
        float4 v = ((const float4*)x)[i];
        *(f16x4*)(xb + (size_t)i * 4) = f16x4{ (f16)v.x, (f16)v.y, (f16)v.z, (f16)v.w };
    }
    for (int i = tid; i < 196608; i += stride) {
        float4 v = ((const float4*)wqkv)[i];
        *(f16x4*)(wqb + (size_t)i * 4) = f16x4{ (f16)v.x, (f16)v.y, (f16)v.z, (f16)v.w };
    }
    for (int i = tid; i < 65536; i += stride) {
        float4 v = ((const float4*)wout)[i];
        *(f16x4*)(wob + (size_t)i * 4) = f16x4{ (f16)v.x, (f16)v.y, (f16)v.z, (f16)v.w };
    }
}

#define W0  asm volatile("s_waitcnt vmcnt(0)" ::: "memory")
#define BAR __builtin_amdgcn_s_barrier()

// ======================= ENGINE A: g10 (r6/r9 verbatim) =======================
// 128x128 tile, BK=64, 4 waves, dbuf 64KB LDS, 2 blocks/CU. Zero-spill verified.

#define A_STAGE(NB) do {                                                        \
    gload16(Ab + kb + sE,          &ldsA[NB][( 0 + wid*8)*64]);                 \
    gload16(Ab + kb + sO + 32768,  &ldsA[NB][(32 + wid*8)*64]);                 \
    gload16(Ab + kb + sE + 65536,  &ldsA[NB][(64 + wid*8)*64]);                 \
    gload16(Ab + kb + sO + 98304,  &ldsA[NB][(96 + wid*8)*64]);                 \
    gload16(Bb + kb + sE,          &ldsB[NB][( 0 + wid*8)*64]);                 \
    gload16(Bb + kb + sO + 32768,  &ldsB[NB][(32 + wid*8)*64]);                 \
    gload16(Bb + kb + sE + 65536,  &ldsB[NB][(64 + wid*8)*64]);                 \
    gload16(Bb + kb + sO + 98304,  &ldsB[NB][(96 + wid*8)*64]);                 \
    kb += 128;                                                                  \
} while (0)

#define A_RD(SET, BUF) do {                                                     \
    _Pragma("unroll") for (int mi = 0; mi < 4; ++mi)                            \
    _Pragma("unroll") for (int kk = 0; kk < 2; ++kk)                            \
        aF##SET[mi][kk] = *(const f16x8*)(&ldsA[BUF][0] + aoff[mi][kk]);        \
    _Pragma("unroll") for (int ni = 0; ni < 4; ++ni)                            \
    _Pragma("unroll") for (int kk = 0; kk < 2; ++kk)                            \
        bF##SET[ni][kk] = *(const f16x8*)(&ldsB[BUF][0] + boff[ni][kk]);        \
} while (0)

#define A_MM(SET, KK, ML, MH_) do {                                             \
    __builtin_amdgcn_s_setprio(1);                                              \
    _Pragma("unroll") for (int mi = ML; mi < MH_; ++mi)                         \
    _Pragma("unroll") for (int ni = 0; ni < 4; ++ni) {                          \
        if constexpr (SWP)                                                      \
            acc[mi][ni] = __builtin_amdgcn_mfma_f32_16x16x32_f16(               \
                bF##SET[ni][KK], aF##SET[mi][KK], acc[mi][ni], 0, 0, 0);        \
        else                                                                    \
            acc[mi][ni] = __builtin_amdgcn_mfma_f32_16x16x32_f16(               \
                aF##SET[mi][KK], bF##SET[ni][KK], acc[mi][ni], 0, 0, 0);        \
    }                                                                           \
    __builtin_amdgcn_s_setprio(0);                                              \
} while (0)

#define A_MM3(SET)   do { A_MM(SET, 0, 0, 2); A_MM(SET, 0, 2, 4); A_MM(SET, 1, 0, 2); } while (0)
#define A_MMLAST(SET) A_MM(SET, 1, 2, 4)

#define A_TILE(CUR, NXT, NB, STG, FINAL) do {                                   \
    if (STG) A_STAGE(NB);                                                       \
    A_MM3(CUR);                                                                 \
    if (!FINAL) { W0; BAR; A_RD(NXT, NB); }                                     \
    A_MMLAST(CUR);                                                              \
} while (0)

template <int MODE, bool SWP, bool QK>
__global__ __launch_bounds__(256, 2) void g10_k(const f16* __restrict__ A0,
                                                const f16* __restrict__ B0,
                                                void* __restrict__ C0,
                                                void* __restrict__ C1,
                                                const float* __restrict__ bias) {
    __shared__ f16 ldsA[2][8192];
    __shared__ f16 ldsB[2][8192];

    const int tid = threadIdx.x;
    const int lane = tid & 63;
    const int wid = tid >> 6;
    const int wr = wid >> 1;
    const int wc = wid & 1;

    const int bid = blockIdx.x;
    int tm, tn;
    if constexpr (MODE == 0 && QK) {
        int swz = (bid & 7) * 256 + (bid >> 3);       // 2048 blocks
        tm = (swz >> 3) * 128; tn = (swz & 7) * 128;
    } else {
        int swz = (bid & 7) * 128 + (bid >> 3);       // 1024 blocks
        tm = (swz >> 2) * 128; tn = (swz & 3) * 128;
    }

    const char* Ab = (const char*)(A0 + (size_t)tm * 512);
    const char* Bb = (const char*)(B0 + (size_t)tn * 512);

    const int u = tid >> 3;
    const int colE = ((tid & 7) ^ ((u & 7) ^ (u >> 3))) * 16;
    const int sE = u * 1024 + colE;
    const int sO = sE ^ 64;
    int kb = 0;

    int aoff[4][2], boff[4][2];
#pragma unroll
    for (int mi = 0; mi < 4; ++mi) {
        int r;
        if constexpr (QK) {
            r = (lane & 15) * 8 + wr * 4 + mi;
        } else {
            r = wr * 64 + mi * 16 + (lane & 15);
        }
#pragma unroll
        for (int kk = 0; kk < 2; ++kk) {
            int c8 = (lane >> 4) + kk * 4;
            aoff[mi][kk] = r * 64 + (c8 ^ ((r & 7) ^ ((r >> 3) & 7))) * 8;
        }
    }
#pragma unroll
    for (int ni = 0; ni < 4; ++ni) {
        int r = wc * 64 + ni * 16 + (lane & 15);
#pragma unroll
        for (int kk = 0; kk < 2; ++kk) {
            int c8 = (lane >> 4) + kk * 4;
            boff[ni][kk] = r * 64 + (c8 ^ ((r & 7) ^ ((r >> 3) & 7))) * 8;
        }
    }

    f32x4 acc[4][4] = {};
    f16x8 aF0[4][2], bF0[4][2], aF1[4][2], bF1[4][2];

    A_STAGE(0);
    W0; BAR;
    A_RD(0, 0);

#pragma unroll 1
    for (int i = 0; i < 3; ++i) {
        A_TILE(0, 1, 1, true, false);
        A_TILE(1, 0, 0, true, false);
    }
    A_TILE(0, 1, 1, true, false);   // t6
    A_TILE(1, 1, 1, false, true);   // t7

    if constexpr (MODE == 0 && QK) {
        const int b = tm >> 12;
        const int lt = (tm & 4095) >> 3;
        f16* dst = (f16*)(tn < 512 ? C0 : C1);
        const int cb = (tn & 511) + wc * 64;
        const int lh0 = lt + (lane >> 4) * 4;
#pragma unroll
        for (int mi = 0; mi < 4; ++mi) {
            int h = wr * 4 + mi;
#pragma unroll
            for (int ni = 0; ni < 4; ++ni) {
                int c = cb + ni * 16 + (lane & 15);
                *(f16x4*)(dst + ((size_t)((b * 8 + h) * 512 + c)) * 512 + lh0) =
                    cvt4(acc[mi][ni]);
            }
        }
    } else {                       // V, swapped
        f16* dst = (f16*)C0;
#pragma unroll
        for (int mi = 0; mi < 4; ++mi) {
            int t = tm + wr * 64 + mi * 16 + (lane & 15);
            int b = t >> 12, l = t & 4095;
            int h = l & 7, lh = l >> 3;
#pragma unroll
            for (int ni = 0; ni < 4; ++ni) {
                int d0 = tn + wc * 64 + ni * 16 + (lane >> 4) * 4;
                *(f16x4*)(dst + ((size_t)((b * 8 + h) * 512 + lh)) * 512 + d0) =
                    cvt4(acc[mi][ni]);
            }
        }
    }
}

// ================== ENGINE S: fused S = QK^T*scale + row softmax ==============
// Per block: one bh, one 128-row c-tile, FULL d=512 width. 8 waves, wave w owns
// d-strip w*64. acc[8][4] = 128 AGPR.  DOUBLE-buffered Q-slice (2x16KB) and
// K-panel (2x64KB) = 160KB LDS exactly; counted vmcnt(10) pipeline: stage(t+1)
// issued before waiting on tile t, so HBM latency + LDS-write drain overlap
// the previous tile's MFMA cluster (r5-verified counted schedule).
// Reductions alias onto ldsQ/ldsK after the main loop.

#define S_STAGE(B) do {                                                         \
    gload16(Qt + kb + soff,           &ldsQ[B][(  0 + wid*8)*64]);              \
    gload16(Qt + kb + soff + 65536,   &ldsQ[B][( 64 + wid*8)*64]);              \
    gload16(Kt + kb + soff,           &ldsK[B][(  0 + wid*8)*64]);              \
    gload16(Kt + kb + soff + 65536,   &ldsK[B][( 64 + wid*8)*64]);              \
    gload16(Kt + kb + soff + 131072,  &ldsK[B][(128 + wid*8)*64]);              \
    gload16(Kt + kb + soff + 196608,  &ldsK[B][(192 + wid*8)*64]);              \
    gload16(Kt + kb + soff + 262144,  &ldsK[B][(256 + wid*8)*64]);              \
    gload16(Kt + kb + soff + 327680,  &ldsK[B][(320 + wid*8)*64]);              \
    gload16(Kt + kb + soff + 393216,  &ldsK[B][(384 + wid*8)*64]);              \
    gload16(Kt + kb + soff + 458752,  &ldsK[B][(448 + wid*8)*64]);              \
    kb += 128;                                                                  \
} while (0)

#define S_RD(KK, B) do {                                                        \
    _Pragma("unroll") for (int ni = 0; ni < 4; ++ni)                            \
        bF[ni] = *(const f16x8*)(&ldsK[B][0] + boff[ni][KK]);                   \
    _Pragma("unroll") for (int mi = 0; mi < 8; ++mi)                            \
        aF[mi] = *(const f16x8*)(&ldsQ[B][0] + aoff[mi][KK]);                   \
} while (0)

#define S_MM do {                                                               \
    __builtin_amdgcn_s_setprio(1);                                              \
    _Pragma("unroll") for (int mi = 0; mi < 8; ++mi)                            \
    _Pragma("unroll") for (int ni = 0; ni < 4; ++ni)                            \
        acc[mi][ni] = __builtin_amdgcn_mfma_f32_16x16x32_f16(                   \
            aF[mi], bF[ni], acc[mi][ni], 0, 0, 0);                              \
    __builtin_amdgcn_s_setprio(0);                                              \
} while (0)

__global__ __launch_bounds__(512) void sfm_k(const f16* __restrict__ Qb,
                                             const f16* __restrict__ Kb,
                                             f16* __restrict__ Pb) {
    __shared__ f16 ldsQ[2][8192];     // 32 KB
    __shared__ f16 ldsK[2][32768];    // 128 KB  (total 160KB exactly)

    const int tid = threadIdx.x;
    const int lane = tid & 63;
    const int wid = tid >> 6;
    const int g = lane >> 4;          // 0..3
    const int li = lane & 15;

    const int bid = blockIdx.x;
    const int swz = (bid & 7) * 32 + (bid >> 3);   // 256 blocks, bijective
    const int bh = swz >> 2, ct = swz & 3;

    const char* Qt = (const char*)(Qb + (size_t)bh * 262144 + (size_t)ct * 128 * 512);
    const char* Kt = (const char*)(Kb + (size_t)bh * 262144);

    const int soff = (tid >> 3) * 1024 +
                     ((((lane & 7) ^ (lane >> 3) ^ wid) & 7) * 16);
    int kb = 0;

    int aoff[8][2], boff[4][2];
#pragma unroll
    for (int mi = 0; mi < 8; ++mi) {
        int r = mi * 16 + li;
        int s3 = (r & 7) ^ ((r >> 3) & 7);
#pragma unroll
        for (int kk = 0; kk < 2; ++kk)
            aoff[mi][kk] = r * 64 + (((g + kk * 4) ^ s3)) * 8;
    }
#pragma unroll
    for (int ni = 0; ni < 4; ++ni) {
        int r = wid * 64 + ni * 16 + li;
        int s3 = (r & 7) ^ ((r >> 3) & 7);
#pragma unroll
        for (int kk = 0; kk < 2; ++kk)
            boff[ni][kk] = r * 64 + (((g + kk * 4) ^ s3)) * 8;
    }

    f32x4 acc[8][4] = {};
    f16x8 aF[8], bF[4];

    S_STAGE(0);
#pragma unroll 1
    for (int t = 0; t < 8; ++t) {
        const int cb = t & 1;
        if (t < 7) {
            S_STAGE(cb ^ 1);
            asm volatile("s_waitcnt vmcnt(10)" ::: "memory");
        } else {
            W0;
        }
        BAR;
        S_RD(0, cb);
        S_MM;
        S_RD(1, cb);
        S_MM;
        BAR;
    }

    // ---- softmax epilogue (fp32); reduce buffers alias dead LDS ----
    float* red  = (float*)&ldsQ[0][0];   // 4 KB (8 waves x 128 rows)
    float* redg = (float*)&ldsK[0][0];   // 512 B

#pragma unroll
    for (int mi = 0; mi < 8; ++mi)
#pragma unroll
        for (int ni = 0; ni < 4; ++ni) acc[mi][ni] *= 0.125f;

    // phase A: wave-partial row max over this wave's 64 cols
#pragma unroll
    for (int mi = 0; mi < 8; ++mi)
#pragma unroll
        for (int j = 0; j < 4; ++j) {
            float v = fmaxf(fmaxf(acc[mi][0][j], acc[mi][1][j]),
                            fmaxf(acc[mi][2][j], acc[mi][3][j]));
#pragma unroll
            for (int off = 1; off < 16; off <<= 1) v = fmaxf(v, __shfl_xor(v, off, 64));
            if (li == 0) red[wid * 128 + mi * 16 + g * 4 + j] = v;
        }
    BAR;
    if (tid < 128) {
        float m = red[tid];
#pragma unroll
        for (int w = 1; w < 8; ++w) m = fmaxf(m, red[w * 128 + tid]);
        redg[tid] = m;
    }
    BAR;

    // phase B: exp + wave-partial row sum
#pragma unroll
    for (int mi = 0; mi < 8; ++mi)
#pragma unroll
        for (int j = 0; j < 4; ++j) {
            float mg = redg[mi * 16 + g * 4 + j];
            float s = 0.f;
#pragma unroll
            for (int ni = 0; ni < 4; ++ni) {
                float e = __expf(acc[mi][ni][j] - mg);
                acc[mi][ni][j] = e;
                s += e;
            }
#pragma unroll
            for (int off = 1; off < 16; off <<= 1) s += __shfl_xor(s, off, 64);
            if (li == 0) red[wid * 128 + mi * 16 + g * 4 + j] = s;
        }
    BAR;
    if (tid < 128) {
        float s = red[tid];
#pragma unroll
        for (int w = 1; w < 8; ++w) s += red[w * 128 + tid];
        redg[tid] = 1.0f / s;
    }
    BAR;

    // phase C: normalize + store P[c][d]
    f16* Pt = Pb + (size_t)bh * 262144;
#pragma unroll
    for (int mi = 0; mi < 8; ++mi)
#pragma unroll
        for (int j = 0; j < 4; ++j) {
            int row = mi * 16 + g * 4 + j;
            float is = redg[row];
            size_t base = (size_t)(ct * 128 + row) * 512 + wid * 64 + li;
#pragma unroll
            for (int ni = 0; ni < 4; ++ni)
                Pt[base + ni * 16] = (f16)(acc[mi][ni][j] * is);
        }
}

// ======================= ENGINE B: g12 (r9 verbatim) ==========================
// 256x256 tile, BK=64, 8 waves, per-wave 128x64, kk-phased single frag set.

#define B_STAGE(NB) do {                                                        \
    gload16(At + soff,          &ldsA2[NB][(  0 + wid*8)*64]);                  \
    gload16(At + soff + 65536,  &ldsA2[NB][( 64 + wid*8)*64]);                  \
    gload16(At + soff + 131072, &ldsA2[NB][(128 + wid*8)*64]);                  \
    gload16(At + soff + 196608, &ldsA2[NB][(192 + wid*8)*64]);                  \
    gload16(Bt + soff,          &ldsB2[NB][(  0 + wid*8)*64]);                  \
    gload16(Bt + soff + 65536,  &ldsB2[NB][( 64 + wid*8)*64]);                  \
    gload16(Bt + soff + 131072, &ldsB2[NB][(128 + wid*8)*64]);                  \
    gload16(Bt + soff + 196608, &ldsB2[NB][(192 + wid*8)*64]);                  \
    At += 128; Bt += 128;                                                       \
} while (0)

#define B_RD12(KK, BUF) do {                                                    \
    _Pragma("unroll") for (int ni = 0; ni < 4; ++ni)                            \
        bF[ni] = *(const f16x8*)(&ldsB2[BUF][0] + boff[ni][KK]);                \
    _Pragma("unroll") for (int mi = 0; mi < 8; ++mi)                            \
        aF[mi] = *(const f16x8*)(&ldsA2[BUF][0] + aoff[mi][KK]);                \
} while (0)

#define B_MM32 do {                                                             \
    __builtin_amdgcn_s_setprio(1);                                              \
    _Pragma("unroll") for (int mi = 0; mi < 8; ++mi)                            \
    _Pragma("unroll") for (int ni = 0; ni < 4; ++ni) {                          \
        if constexpr (SWP)                                                      \
            acc[mi][ni] = __builtin_amdgcn_mfma_f32_16x16x32_f16(               \
                bF[ni], aF[mi], acc[mi][ni], 0, 0, 0);                          \
        else                                                                    \
            acc[mi][ni] = __builtin_amdgcn_mfma_f32_16x16x32_f16(               \
                aF[mi], bF[ni], acc[mi][ni], 0, 0, 0);                          \
    }                                                                           \
    __builtin_amdgcn_s_setprio(0);                                              \
} while (0)

#define B_TILE(CB, NB, STG, FINAL) do {                                         \
    B_RD12(0, CB);                                                              \
    if (STG) B_STAGE(NB);                                                       \
    B_MM32;                                                                     \
    B_RD12(1, CB);                                                              \
    B_MM32;                                                                     \
    if (!FINAL) { W0; BAR; }                                                    \
} while (0)

// MODE 2: Y = P V per bh (normal, f16 out to y[token][c])
// MODE 3: out = y w_out^T + b_out (swapped, f32 out)
template <int MODE, bool SWP>
__global__ __launch_bounds__(512) void g12_k(const f16* __restrict__ A0,
                                             const f16* __restrict__ B0,
                                             void* __restrict__ C0,
                                             const float* __restrict__ bias) {
    __shared__ f16 ldsA2[2][16384];
    __shared__ f16 ldsB2[2][16384];

    const int tid = threadIdx.x;
    const int lane = tid & 63;
    const int wid = tid >> 6;
    const int wr = wid >> 2;
    const int wc = wid & 3;

    const int bid = blockIdx.x;
    int tm, tn, bh = 0;
    if constexpr (MODE == 2) {
        int swz = (bid & 7) * 32 + (bid >> 3);        // 256 blocks
        bh = swz >> 2; tm = ((swz >> 1) & 1) * 256; tn = (swz & 1) * 256;
    } else {
        int swz = (bid & 7) * 32 + (bid >> 3);        // 256 blocks
        tm = (swz >> 1) * 256; tn = (swz & 1) * 256;
    }

    const size_t bhoff = (MODE == 2) ? (size_t)bh * 262144 : 0;
    const char* At = (const char*)(A0 + bhoff + (size_t)tm * 512);
    const char* Bt = (const char*)(B0 + bhoff + (size_t)tn * 512);

    const int soff = wid * 8192 + (lane >> 3) * 1024 +
                     ((((lane & 7) ^ (lane >> 3) ^ wid) & 7) * 16);

    int aoff[8][2], boff[4][2];
#pragma unroll
    for (int mi = 0; mi < 8; ++mi) {
        int r = wr * 128 + mi * 16 + (lane & 15);
        int s3 = (r & 7) ^ ((r >> 3) & 7);
#pragma unroll
        for (int kk = 0; kk < 2; ++kk)
            aoff[mi][kk] = r * 64 + ((((lane >> 4) + kk * 4) ^ s3)) * 8;
    }
#pragma unroll
    for (int ni = 0; ni < 4; ++ni) {
        int r = wc * 64 + ni * 16 + (lane & 15);
        int s3 = (r & 7) ^ ((r >> 3) & 7);
#pragma unroll
        for (int kk = 0; kk < 2; ++kk)
            boff[ni][kk] = r * 64 + ((((lane >> 4) + kk * 4) ^ s3)) * 8;
    }

    f32x4 acc[8][4] = {};
    f16x8 aF[8], bF[4];

    B_STAGE(0);
    W0; BAR;

#pragma unroll 1
    for (int i = 0; i < 3; ++i) {
        B_TILE(0, 1, true, false);
        B_TILE(1, 0, true, false);
    }
    B_TILE(0, 1, true, false);    // t6
    B_TILE(1, 1, false, true);    // t7

    if constexpr (MODE == 2) {
        f16* yb = (f16*)C0;
        const int b = bh >> 3, h = bh & 7;
#pragma unroll
        for (int mi = 0; mi < 8; ++mi) {
            int c0 = tm + wr * 128 + mi * 16 + (lane >> 4) * 4;
#pragma unroll
            for (int ni = 0; ni < 4; ++ni) {
                int l = tn + wc * 64 + ni * 16 + (lane & 15);
                size_t tok = (size_t)b * 4096 + (size_t)l * 8 + h;
                *(f16x4*)(yb + tok * 512 + c0) = cvt4(acc[mi][ni]);
            }
        }
    } else {
        float* O = (float*)C0;
#pragma unroll
        for (int mi = 0; mi < 8; ++mi) {
            int m = tm + wr * 128 + mi * 16 + (lane & 15);
#pragma unroll
            for (int ni = 0; ni < 4; ++ni) {
                int n0 = tn + wc * 64 + ni * 16 + (lane >> 4) * 4;
                float4 bv = *(const float4*)(bias + n0);
                f32x4 v = acc[mi][ni];
                v[0] += bv.x; v[1] += bv.y; v[2] += bv.z; v[3] += bv.w;
                *(f32x4*)(O + (size_t)m * 512 + n0) = v;
            }
        }
    }
}

// ---------------- launch ------------------------------------------------------
extern "C" void kernel_launch(void* const* d_in, const int* in_sizes, int n_in,
                              void* d_out, int out_size, void* d_ws, size_t ws_size,
                              hipStream_t stream) {
    const float* x = (const float*)d_in[0];
    const float* wqkv = (const float*)d_in[1];
    const float* wout = (const float*)d_in[2];
    const float* bout = (const float*)d_in[3];
    float* out = (float*)d_out;
    char* ws = (char*)d_ws;
    const size_t MBs = 1u << 20;

    f16* xb  = (f16*)(ws + 0);            // 32MB
    f16* wqb = (f16*)(ws + 32 * MBs);     // 1.5MB
    f16* wob = (f16*)(ws + 34 * MBs);     // 0.5MB
    f16* Qb  = (f16*)(ws + 35 * MBs);     // 32MB
    f16* Kb  = (f16*)(ws + 67 * MBs);     // 32MB
    f16* Vb  = (f16*)(ws + 99 * MBs);     // 32MB
    f16* Pb  = xb;                        // alias: xb dead after V GEMM
    f16* yb  = Qb;                        // alias: Q dead after sfm

    prep_k<<<1024, 256, 0, stream>>>(x, wqkv, wout, xb, wqb, wob);
    g10_k<0, false, true><<<2048, 256, 0, stream>>>(xb, wqb, Qb, Kb, nullptr);
    g10_k<0, true, false><<<1024, 256, 0, stream>>>(xb, wqb + (size_t)1024 * 512, Vb, nullptr, nullptr);
    sfm_k<<<256, 512, 0, stream>>>(Qb, Kb, Pb);
    g12_k<2, false><<<256, 512, 0, stream>>>(Pb, Vb, yb, nullptr);
    g12_k<3, true><<<256, 512, 0, stream>>>(yb, wob, out, bout);
}